// Round 6
// baseline (495.284 us; speedup 1.0000x reference)
//
#include <hip/hip_runtime.h>
#include <cmath>

// MHA fused forward, MI355X gfx950.
// R5: (a) all GEMMs get 2-phase double-buffered prefetch (stage t+1 issued
//     before compute t; one barrier/step drains it after compute) and V is
//     merged into the QK launch (z=2). (b) attn rewritten on 32x32x16 MFMA:
//     q stays lane-local (lane&31), softmax = in-lane 32 + one shfl_xor(32),
//     P redistributed to the PV B-operand via shfl_xor(32) + selects -> sP
//     LDS buffer deleted (48KB LDS, 3 blocks/CU), exp2-domain softmax.
// Numerics: split-bf16 hi/lo 3-term for Q/K projections and QK^T (scores
// std ~784 need ~fp32; V/PV/O-proj plain bf16).

typedef __bf16 bf16_t;
typedef __bf16 bf16x2 __attribute__((ext_vector_type(2)));
typedef __bf16 bf16x4 __attribute__((ext_vector_type(4)));
typedef __bf16 bf16x8 __attribute__((ext_vector_type(8)));
typedef float f32x2 __attribute__((ext_vector_type(2)));
typedef float f32x4 __attribute__((ext_vector_type(4)));
typedef float f32x16 __attribute__((ext_vector_type(16)));
typedef unsigned int u32;
typedef u32 u32x4 __attribute__((ext_vector_type(4)));
typedef const __attribute__((address_space(1))) u32* gaddr_t;
typedef __attribute__((address_space(3))) u32* saddr_t;

struct RopeTab { float inv[32]; };

// ---------------- pre-pass: fp32 -> bf16 hi (+lo) ----------------
template<bool LO>
__global__ __launch_bounds__(256) void split_k(const float* __restrict__ in,
                                               bf16_t* __restrict__ hi,
                                               bf16_t* __restrict__ lo)
{
  const int i = blockIdx.x * 256 + threadIdx.x;
  const f32x4 u = *(const f32x4*)(in + (size_t)i * 4);
  bf16x4 h, l;
  #pragma unroll
  for (int j = 0; j < 4; ++j) {
    const bf16_t hb = (bf16_t)u[j];
    h[j] = hb;
    if (LO) l[j] = (bf16_t)(u[j] - (float)hb);
  }
  *(bf16x4*)(hi + (size_t)i * 4) = h;
  if (LO) *(bf16x4*)(lo + (size_t)i * 4) = l;
}

// ---------------- pre-pass: RoPE cos/sin table [pos][32 pairs] ----------------
__global__ __launch_bounds__(256) void rope_tab_k(RopeTab tab, float* __restrict__ T)
{
  const int i = blockIdx.x * 256 + threadIdx.x;   // 2048*32 entries
  const int p = i >> 5, d2 = i & 31;
  float sn, cs;
  sincosf((float)p * tab.inv[d2], &sn, &cs);
  T[(size_t)i * 2]     = cs;
  T[(size_t)i * 2 + 1] = sn;
}

// ------------- QKV projection GEMM (B^T), 2-phase dbuf prefetch -------------
// z=0: Q (3-seg split, RoPE epilogue), z=1: K (same), z=2: V (1 seg, V^T out).
__global__ __launch_bounds__(256) void gemm_qkv(
    const bf16_t* __restrict__ Xh, const bf16_t* __restrict__ Xl,
    const bf16_t* __restrict__ QWh, const bf16_t* __restrict__ QWl,
    const bf16_t* __restrict__ KWh, const bf16_t* __restrict__ KWl,
    const bf16_t* __restrict__ VWh,
    const int* __restrict__ tokpos, const float* __restrict__ ropeT,
    bf16_t* __restrict__ Oq_h, bf16_t* __restrict__ Oq_l,
    bf16_t* __restrict__ Ok_h, bf16_t* __restrict__ Ok_l,
    bf16_t* __restrict__ Vt)
{
  __shared__ __align__(16) bf16_t sA[2][128 * 64];
  __shared__ __align__(16) bf16_t sB[2][128 * 64];

  const int tid = threadIdx.x;
  const int lane = tid & 63, wv = tid >> 6;
  const int wr = wv >> 1, wc = wv & 1;
  const int la = lane & 15, lb = lane >> 4;
  const int row0 = blockIdx.x * 128, col0 = blockIdx.y * 128;
  const int z = blockIdx.z;

  const int srow = wv * 32 + (lane >> 3);   // + i*8
  const int schk = lane & 7;                // physical 16B chunk within row

  f32x4 acc[4][4] = {};

  const int NT = (z == 2) ? 16 : 48;        // steps of BK=64 (3 segs for Q/K)

  auto STAGE = [&](int step, int buf) {
    const int seg = step >> 4;
    const int k0 = (step & 15) << 6;
    const bf16_t* Ap = (z < 2 && seg == 2) ? Xl : Xh;
    const bf16_t* Wp = (z == 2) ? VWh
                     : (z == 1) ? ((seg == 1) ? KWl : KWh)
                                : ((seg == 1) ? QWl : QWh);
    #pragma unroll
    for (int i = 0; i < 4; ++i) {
      const int r = srow + i * 8;
      const int cs_ = (schk ^ (r & 7)) * 8;       // inverse-swizzled source col
      __builtin_amdgcn_global_load_lds(
          (gaddr_t)(Ap + (size_t)(row0 + r) * 1024 + k0 + cs_),
          (saddr_t)(&sA[buf][0] + wv * 2048 + i * 512), 16, 0, 0);
      __builtin_amdgcn_global_load_lds(
          (gaddr_t)(Wp + (size_t)(col0 + r) * 1024 + k0 + cs_),
          (saddr_t)(&sB[buf][0] + wv * 2048 + i * 512), 16, 0, 0);
    }
  };

  STAGE(0, 0);
  for (int t = 0; t < NT; ++t) {
    __syncthreads();                 // drains stage(t) (own vmcnt), frees buf
    if (t + 1 < NT) STAGE(t + 1, (t + 1) & 1);
    const bf16_t* cA = &sA[t & 1][0];
    const bf16_t* cB = &sB[t & 1][0];
    #pragma unroll
    for (int ks = 0; ks < 2; ++ks) {
      bf16x8 af[4];
      #pragma unroll
      for (int m = 0; m < 4; ++m) {
        const int r = wr * 64 + m * 16 + la;
        af[m] = *(const bf16x8*)&cA[r * 64 + (((ks * 4 + lb) ^ (la & 7)) * 8)];
      }
      #pragma unroll
      for (int n = 0; n < 4; ++n) {
        const int r = wc * 64 + n * 16 + la;
        const bf16x8 bfr = *(const bf16x8*)&cB[r * 64 + (((ks * 4 + lb) ^ (la & 7)) * 8)];
        #pragma unroll
        for (int m = 0; m < 4; ++m)
          acc[m][n] = __builtin_amdgcn_mfma_f32_16x16x32_bf16(af[m], bfr, acc[m][n], 0, 0, 0);
      }
    }
  }

  // ---- epilogue ----
  #pragma unroll
  for (int n = 0; n < 4; ++n) {
    const int gn = col0 + wc * 64 + n * 16 + la;
    #pragma unroll
    for (int m = 0; m < 4; ++m) {
      const int gm0 = row0 + wr * 64 + m * 16 + lb * 4;
      if (z == 2) {
        // V^T layout: [B,H,D,S], packed 8B stores
        const int b = gm0 >> 11, s0 = gm0 & 2047;
        const int h = gn >> 6, d = gn & 63;
        bf16x4 v;
        #pragma unroll
        for (int j = 0; j < 4; ++j) v[j] = (bf16_t)acc[m][n][j];
        *(bf16x4*)&Vt[(((size_t)b * 16 + h) * 64 + d) * 2048 + s0] = v;
      } else {
        const int d = gn & 63, h = gn >> 6;
        const bool odd = d & 1;
        bf16_t* Oh = z ? Ok_h : Oq_h;
        bf16_t* Ol = z ? Ok_l : Oq_l;
        #pragma unroll
        for (int j = 0; j < 4; ++j) {
          const int gm = gm0 + j;
          const float t = acc[m][n][j];
          const float other = __shfl_xor(t, 1, 64);   // partner column d^1
          const int pos = tokpos[gm];
          const f32x2 cs2 = *(const f32x2*)&ropeT[((size_t)pos << 6) + ((d >> 1) << 1)];
          const float r = odd ? (other * cs2[1] + t * cs2[0])
                              : (t * cs2[0] - other * cs2[1]);
          const bf16_t hb = (bf16_t)r;
          const int b = gm >> 11, s = gm & 2047;
          const size_t oi = (((size_t)b * 16 + h) * 2048 + s) * 64 + d;
          Oh[oi] = hb;
          Ol[oi] = (bf16_t)(r - (float)hb);
        }
      }
    }
  }
}

// ------------- O projection GEMM (bf16 A, fp32 out), 2-phase dbuf -------------
__global__ __launch_bounds__(256) void gemm_o(
    const bf16_t* __restrict__ Ag, const bf16_t* __restrict__ Wg,
    float* __restrict__ Of)
{
  __shared__ __align__(16) bf16_t sA[2][128 * 64];
  __shared__ __align__(16) bf16_t sB[2][128 * 64];

  const int tid = threadIdx.x;
  const int lane = tid & 63, wv = tid >> 6;
  const int wr = wv >> 1, wc = wv & 1;
  const int la = lane & 15, lb = lane >> 4;
  const int row0 = blockIdx.x * 128, col0 = blockIdx.y * 128;

  const int srow = wv * 32 + (lane >> 3);
  const int schk = lane & 7;

  f32x4 acc[4][4] = {};

  auto STAGE = [&](int t, int buf) {
    const int k0 = t << 6;
    #pragma unroll
    for (int i = 0; i < 4; ++i) {
      const int r = srow + i * 8;
      const int cs_ = (schk ^ (r & 7)) * 8;
      __builtin_amdgcn_global_load_lds(
          (gaddr_t)(Ag + (size_t)(row0 + r) * 1024 + k0 + cs_),
          (saddr_t)(&sA[buf][0] + wv * 2048 + i * 512), 16, 0, 0);
      __builtin_amdgcn_global_load_lds(
          (gaddr_t)(Wg + (size_t)(col0 + r) * 1024 + k0 + cs_),
          (saddr_t)(&sB[buf][0] + wv * 2048 + i * 512), 16, 0, 0);
    }
  };

  STAGE(0, 0);
  for (int t = 0; t < 16; ++t) {
    __syncthreads();
    if (t + 1 < 16) STAGE(t + 1, (t + 1) & 1);
    const bf16_t* cA = &sA[t & 1][0];
    const bf16_t* cB = &sB[t & 1][0];
    #pragma unroll
    for (int ks = 0; ks < 2; ++ks) {
      bf16x8 af[4];
      #pragma unroll
      for (int m = 0; m < 4; ++m) {
        const int r = wr * 64 + m * 16 + la;
        af[m] = *(const bf16x8*)&cA[r * 64 + (((ks * 4 + lb) ^ (la & 7)) * 8)];
      }
      #pragma unroll
      for (int n = 0; n < 4; ++n) {
        const int r = wc * 64 + n * 16 + la;
        const bf16x8 bfr = *(const bf16x8*)&cB[r * 64 + (((ks * 4 + lb) ^ (la & 7)) * 8)];
        #pragma unroll
        for (int m = 0; m < 4; ++m)
          acc[m][n] = __builtin_amdgcn_mfma_f32_16x16x32_bf16(af[m], bfr, acc[m][n], 0, 0, 0);
      }
    }
  }

  #pragma unroll
  for (int n = 0; n < 4; ++n) {
    const int gn = col0 + wc * 64 + n * 16 + la;
    #pragma unroll
    for (int m = 0; m < 4; ++m) {
      const int gm0 = row0 + wr * 64 + m * 16 + lb * 4;
      #pragma unroll
      for (int j = 0; j < 4; ++j)
        Of[(size_t)(gm0 + j) * 1024 + gn] = acc[m][n][j];
    }
  }
}

// XOR swizzle for 64-elem-wide bf16 LDS tiles (row = 128B).
__device__ __forceinline__ int SW(int e) { return e ^ (((e >> 6) & 7) << 3); }

__device__ __forceinline__ u32 pk2(float a, float b) {
  bf16x2 t; t[0] = (bf16_t)a; t[1] = (bf16_t)b;
  return __builtin_bit_cast(u32, t);
}

// Flash attention, causal, split-bf16 QK^T, swapped operands, 32x32x16 MFMA.
// Grid 1024 blocks x 256 threads (4 waves x 32 q-rows = QBLK 128), KVBLK=64.
// Per lane: q = qb*128 + wv*32 + (lane&31) FIXED; l5 = lane>>5 selects the
// kv mod-8 half {0..3 / 4..7}. S^T frag rows kv = (r&3)+8*(r>>2)+4*l5 (+32*hv).
// PV B-operand built in-register: pack P to bf16 pairs, exchange the other
// mod-8 half via shfl_xor(32). No P LDS buffer.
__global__ __launch_bounds__(256) void attn_kernel(
    const bf16_t* __restrict__ Qhi, const bf16_t* __restrict__ Qlo,
    const bf16_t* __restrict__ Khi, const bf16_t* __restrict__ Klo,
    const bf16_t* __restrict__ Vt, bf16_t* __restrict__ O)
{
  __shared__ __align__(16) bf16_t sKV[2][3 * 4096];  // Kh | Kl | Vt

  // XCD-aware remap + longest-first qb
  const int linear = (int)blockIdx.y * (int)gridDim.x + (int)blockIdx.x;
  const int xcd = linear & 7;
  const int pos = linear >> 3;            // 0..127
  const int bh  = xcd * 8 + (pos >> 4);   // [0,64)
  const int qb  = 15 - (pos & 15);
  const int b = bh >> 4, h = bh & 15;

  const size_t base = (size_t)bh * 2048 * 64;
  const bf16_t* Qh_ = Qhi + base;
  const bf16_t* Ql_ = Qlo + base;
  const bf16_t* Kh_ = Khi + base;
  const bf16_t* Kl_ = Klo + base;
  const bf16_t* Vt_ = Vt + base;          // [64 d][2048 s]

  const int tid = threadIdx.x, wv = tid >> 6, lane = tid & 63;
  const int q32 = lane & 31, l5 = lane >> 5;
  const int q = qb * 128 + wv * 32 + q32;

  // staging geometry: 6 x 16B per thread covers 24KB (Kh,Kl,Vt x 8KB)
  auto STAGE = [&](int kvb, int buf) {
    const int kv0 = kvb * 64;
    bf16_t* dst = &sKV[buf][0];
    #pragma unroll
    for (int i = 0; i < 2; ++i) {
      const int e0 = (i * 4 + wv) * 512;          // wave-uniform chunk base
      const int e = e0 + lane * 8;
      const int r = e >> 6;                       // tile row 0..63
      const int csw = ((e >> 3) & 7) ^ (r & 7);   // inverse-swizzled chunk
      const int ks = r * 64 + csw * 8;
      __builtin_amdgcn_global_load_lds((gaddr_t)(Kh_ + (size_t)kv0 * 64 + ks),
                                       (saddr_t)(dst + e0), 16, 0, 0);
      __builtin_amdgcn_global_load_lds((gaddr_t)(Kl_ + (size_t)kv0 * 64 + ks),
                                       (saddr_t)(dst + 4096 + e0), 16, 0, 0);
      __builtin_amdgcn_global_load_lds((gaddr_t)(Vt_ + (size_t)r * 2048 + kv0 + csw * 8),
                                       (saddr_t)(dst + 8192 + e0), 16, 0, 0);
    }
  };

  const int nt = 2 * qb + 2;
  STAGE(0, 0);

  // Q fragments: B-operand, lane holds Q[k = kc*16 + l5*8 + 0..7][q]
  bf16x8 qh[4], ql[4];
  #pragma unroll
  for (int kc = 0; kc < 4; ++kc) {
    qh[kc] = *(const bf16x8*)&Qh_[(size_t)q * 64 + kc * 16 + l5 * 8];
    ql[kc] = *(const bf16x8*)&Ql_[(size_t)q * 64 + kc * 16 + l5 * 8];
  }

  f32x16 oacc[2] = {};        // O^T[d = 32*dh + (r&3)+8*(r>>2)+4*l5][q]
  float m2 = -1e30f, l = 0.f; // exp2-domain running max / denom
  const float CSC = 0.125f * 1.44269504089f;

  for (int kvb = 0; kvb < nt; ++kvb) {
    const int kv0 = kvb * 64;
    __syncthreads();                       // stage(kvb) ready; buf^1 free
    if (kvb + 1 < nt) STAGE(kvb + 1, (kvb + 1) & 1);

    const bf16_t* sKh = &sKV[kvb & 1][0];
    const bf16_t* sKl = sKh + 4096;
    const bf16_t* sVt = sKh + 8192;

    // S^T = K Q^T (3-term split)
    f32x16 sacc[2] = {};
    __builtin_amdgcn_s_setprio(1);
    #pragma unroll
    for (int hv = 0; hv < 2; ++hv) {
      #pragma unroll
      for (int kc = 0; kc < 4; ++kc) {
        const int rr = SW((hv * 32 + q32) * 64 + kc * 16 + l5 * 8);
        const bf16x8 kh = *(const bf16x8*)&sKh[rr];
        const bf16x8 kl = *(const bf16x8*)&sKl[rr];
        sacc[hv] = __builtin_amdgcn_mfma_f32_32x32x16_bf16(kh, qh[kc], sacc[hv], 0, 0, 0);
        sacc[hv] = __builtin_amdgcn_mfma_f32_32x32x16_bf16(kl, qh[kc], sacc[hv], 0, 0, 0);
        sacc[hv] = __builtin_amdgcn_mfma_f32_32x32x16_bf16(kh, ql[kc], sacc[hv], 0, 0, 0);
      }
    }
    __builtin_amdgcn_s_setprio(0);

    // scale into exp2 domain + causal mask (only possibly-diagonal tiles)
    if (kvb >= 2 * qb) {
      #pragma unroll
      for (int hv = 0; hv < 2; ++hv)
        #pragma unroll
        for (int r = 0; r < 16; ++r) {
          const int kv = kv0 + 32 * hv + (r & 3) + 8 * (r >> 2) + 4 * l5;
          sacc[hv][r] = (kv <= q) ? sacc[hv][r] * CSC : -1e30f;
        }
    } else {
      #pragma unroll
      for (int hv = 0; hv < 2; ++hv)
        #pragma unroll
        for (int r = 0; r < 16; ++r) sacc[hv][r] *= CSC;
    }

    // row max: 32 in-lane + one cross-half shfl
    float red = sacc[0][0];
    #pragma unroll
    for (int hv = 0; hv < 2; ++hv)
      #pragma unroll
      for (int r = 0; r < 16; ++r) red = fmaxf(red, sacc[hv][r]);
    red = fmaxf(red, __shfl_xor(red, 32, 64));

    // defer-max (THR = 8*log2e ~ 11.5 in exp2 domain)
    const float mn = fmaxf(m2, red);
    if (!__all(mn - m2 <= 11.5f)) {
      const float sf = exp2f(m2 - mn);
      m2 = mn;
      l *= sf;
      #pragma unroll
      for (int dh = 0; dh < 2; ++dh)
        #pragma unroll
        for (int r = 0; r < 16; ++r) oacc[dh][r] *= sf;
    }

    float rs = 0.f;
    #pragma unroll
    for (int hv = 0; hv < 2; ++hv)
      #pragma unroll
      for (int r = 0; r < 16; ++r) {
        const float p = exp2f(sacc[hv][r] - m2);
        sacc[hv][r] = p;
        rs += p;
      }
    rs += __shfl_xor(rs, 32, 64);
    l += rs;

    // pack P to bf16 pairs: pk[hv][g][j] covers kv = 32hv+8g+4*l5+{2j,2j+1}
    u32 pk[2][4][2];
    #pragma unroll
    for (int hv = 0; hv < 2; ++hv)
      #pragma unroll
      for (int g = 0; g < 4; ++g) {
        pk[hv][g][0] = pk2(sacc[hv][4 * g], sacc[hv][4 * g + 1]);
        pk[hv][g][1] = pk2(sacc[hv][4 * g + 2], sacc[hv][4 * g + 3]);
      }

    // O^T += V^T P^T, B-frag per k-chunk c assembled in-register
    __builtin_amdgcn_s_setprio(1);
    #pragma unroll
    for (int c = 0; c < 4; ++c) {
      const int i0 = 2 * c, i1 = 2 * c + 1;
      const int h0 = i0 >> 2, g0 = i0 & 3, h1 = i1 >> 2, g1 = i1 & 3;
      const u32 own_a = l5 ? pk[h1][g1][0] : pk[h0][g0][0];
      const u32 own_b = l5 ? pk[h1][g1][1] : pk[h0][g0][1];
      const u32 snd_a = l5 ? pk[h0][g0][0] : pk[h1][g1][0];
      const u32 snd_b = l5 ? pk[h0][g0][1] : pk[h1][g1][1];
      const u32 rcv_a = (u32)__shfl_xor((int)snd_a, 32, 64);
      const u32 rcv_b = (u32)__shfl_xor((int)snd_b, 32, 64);
      u32x4 w4;
      w4[0] = l5 ? rcv_a : own_a;   // kv offset +0..1 (mod-8 half 0)
      w4[1] = l5 ? rcv_b : own_b;   // +2..3
      w4[2] = l5 ? own_a : rcv_a;   // +4..5 (mod-8 half 1)
      w4[3] = l5 ? own_b : rcv_b;   // +6..7
      const bf16x8 pfrag = __builtin_bit_cast(bf16x8, w4);
      #pragma unroll
      for (int dh = 0; dh < 2; ++dh) {
        const int rr = SW((dh * 32 + q32) * 64 + c * 16 + l5 * 8);
        const bf16x8 va = *(const bf16x8*)&sVt[rr];
        oacc[dh] = __builtin_amdgcn_mfma_f32_32x32x16_bf16(va, pfrag, oacc[dh], 0, 0, 0);
      }
    }
    __builtin_amdgcn_s_setprio(0);
  }

  // epilogue: O[b,s,h,d] bf16, packed b64 (d groups of 4)
  const float inv_l = 1.0f / l;
  #pragma unroll
  for (int dh = 0; dh < 2; ++dh)
    #pragma unroll
    for (int g = 0; g < 4; ++g) {
      bf16x4 ov;
      #pragma unroll
      for (int j = 0; j < 4; ++j) ov[j] = (bf16_t)(oacc[dh][4 * g + j] * inv_l);
      const int d0 = 32 * dh + 8 * g + 4 * l5;
      *(bf16x4*)&O[(((size_t)b * 2048 + q) * 16 + h) * 64 + d0] = ov;
    }
}

extern "C" void kernel_launch(void* const* d_in, const int* in_sizes, int n_in,
                              void* d_out, int out_size, void* d_ws, size_t ws_size,
                              hipStream_t stream)
{
  const float* x      = (const float*)d_in[0];
  const int*   tokpos = (const int*)d_in[1];
  const float* qw     = (const float*)d_in[2];
  const float* kw     = (const float*)d_in[3];
  const float* vw     = (const float*)d_in[4];
  const float* ow     = (const float*)d_in[5];
  float* out = (float*)d_out;

  const size_t E  = (size_t)4 * 16 * 2048 * 64;  // 8388608 elems per activation
  const size_t W1 = (size_t)1024 * 1024;         // weight elems
  bf16_t* base = (bf16_t*)d_ws;
  bf16_t* Qhi = base;
  bf16_t* Qlo = base + E;
  bf16_t* Khi = base + 2 * E;
  bf16_t* Klo = base + 3 * E;
  bf16_t* Vt  = base + 4 * E;        // [B,H,D,S]
  bf16_t* Xh  = base + 5 * E;
  bf16_t* Xl  = base + 6 * E;
  bf16_t* QWh = base + 7 * E;
  bf16_t* QWl = QWh + W1;
  bf16_t* KWh = QWh + 2 * W1;
  bf16_t* KWl = QWh + 3 * W1;
  bf16_t* VWh = QWh + 4 * W1;
  bf16_t* OWh = QWh + 5 * W1;
  float*  ropeT = (float*)(QWh + 6 * W1);        // 2048*64 floats
  bf16_t* O = Xh;                                 // alias: X dead before attn

  RopeTab tab;
  for (int i = 0; i < 32; ++i)
    tab.inv[i] = (float)pow(10000.0, -(double)i / 32.0);

  // pre-passes
  split_k<true ><<<8192, 256, 0, stream>>>(x,  Xh,  Xl);
  split_k<true ><<<1024, 256, 0, stream>>>(qw, QWh, QWl);
  split_k<true ><<<1024, 256, 0, stream>>>(kw, KWh, KWl);
  split_k<false><<<1024, 256, 0, stream>>>(vw, VWh, nullptr);
  split_k<false><<<1024, 256, 0, stream>>>(ow, OWh, nullptr);
  rope_tab_k<<<256, 256, 0, stream>>>(tab, ropeT);

  // Q, K, V projections in one launch (z selects); RoPE fused for Q/K
  gemm_qkv<<<dim3(64, 8, 3), 256, 0, stream>>>(
      Xh, Xl, QWh, QWl, KWh, KWl, VWh, tokpos, ropeT,
      Qhi, Qlo, Khi, Klo, Vt);
  // attention (1024 blocks x 256 threads, XCD-remapped inside)
  attn_kernel<<<dim3(16, 64), 256, 0, stream>>>(Qhi, Qlo, Khi, Klo, Vt, O);
  // output projection -> fp32 d_out
  gemm_o<<<dim3(64, 8), 256, 0, stream>>>(O, OWh, out);
}

// Round 7
// 339.115 us; speedup vs baseline: 1.4605x; 1.4605x over previous
//
#include <hip/hip_runtime.h>
#include <cmath>

// MHA fused forward, MI355X gfx950.
// R6: REVERT the R5 GEMM dbuf (m132 lesson: 64KB LDS halves blocks/CU ->
//     MfmaUtil 30->17.5%). GEMMs back to the R4 single-buffered 32KB
//     2-barrier m97 structure + __launch_bounds__(256,4). QKV stays merged
//     (z=3). Pre-passes fused into 2 launches. attn kept from R5 (32x32
//     MFMA, register-redistributed P, no sP LDS) to isolate its effect.
// Numerics: split-bf16 hi/lo 3-term for Q/K projections and QK^T.

typedef __bf16 bf16_t;
typedef __bf16 bf16x2 __attribute__((ext_vector_type(2)));
typedef __bf16 bf16x4 __attribute__((ext_vector_type(4)));
typedef __bf16 bf16x8 __attribute__((ext_vector_type(8)));
typedef float f32x2 __attribute__((ext_vector_type(2)));
typedef float f32x4 __attribute__((ext_vector_type(4)));
typedef float f32x16 __attribute__((ext_vector_type(16)));
typedef unsigned int u32;
typedef u32 u32x4 __attribute__((ext_vector_type(4)));
typedef const __attribute__((address_space(1))) u32* gaddr_t;
typedef __attribute__((address_space(3))) u32* saddr_t;

struct RopeTab { float inv[32]; };

// ---------------- fused pre-pass ----------------
// blocks [0,8192): x -> Xh,Xl ; [8192,9216): qw -> QWh,QWl ;
// [9216,10240): kw -> KWh,KWl ; [10240,11264): vw -> VWh ;
// [11264,12288): ow -> OWh ; [12288,12544): RoPE cos/sin table.
__device__ __forceinline__ void split4(const float* __restrict__ in,
                                       bf16_t* __restrict__ hi,
                                       bf16_t* __restrict__ lo, bool LO,
                                       int blk, int tid)
{
  const int i = blk * 256 + tid;
  const f32x4 u = *(const f32x4*)(in + (size_t)i * 4);
  bf16x4 h, l;
  #pragma unroll
  for (int j = 0; j < 4; ++j) {
    const bf16_t hb = (bf16_t)u[j];
    h[j] = hb;
    if (LO) l[j] = (bf16_t)(u[j] - (float)hb);
  }
  *(bf16x4*)(hi + (size_t)i * 4) = h;
  if (LO) *(bf16x4*)(lo + (size_t)i * 4) = l;
}

__global__ __launch_bounds__(256) void prep_k(
    const float* __restrict__ x,  const float* __restrict__ qw,
    const float* __restrict__ kw, const float* __restrict__ vw,
    const float* __restrict__ ow, RopeTab tab,
    bf16_t* __restrict__ Xh,  bf16_t* __restrict__ Xl,
    bf16_t* __restrict__ QWh, bf16_t* __restrict__ QWl,
    bf16_t* __restrict__ KWh, bf16_t* __restrict__ KWl,
    bf16_t* __restrict__ VWh, bf16_t* __restrict__ OWh,
    float* __restrict__ ropeT)
{
  const int bid = blockIdx.x, tid = threadIdx.x;
  if (bid < 8192)       split4(x,  Xh,  Xl,  true,  bid,         tid);
  else if (bid < 9216)  split4(qw, QWh, QWl, true,  bid - 8192,  tid);
  else if (bid < 10240) split4(kw, KWh, KWl, true,  bid - 9216,  tid);
  else if (bid < 11264) split4(vw, VWh, nullptr, false, bid - 10240, tid);
  else if (bid < 12288) split4(ow, OWh, nullptr, false, bid - 11264, tid);
  else {
    const int i = (bid - 12288) * 256 + tid;   // 2048*32 entries
    const int p = i >> 5, d2 = i & 31;
    float sn, cs;
    sincosf((float)p * tab.inv[d2], &sn, &cs);
    ropeT[(size_t)i * 2]     = cs;
    ropeT[(size_t)i * 2 + 1] = sn;
  }
}

// ------------- QKV projection GEMM (B^T), m97 single-buffer -------------
// z=0: Q (3-seg split, RoPE epilogue), z=1: K (same), z=2: V (1 seg, V^T out).
__global__ __launch_bounds__(256, 4) void gemm_qkv(
    const bf16_t* __restrict__ Xh, const bf16_t* __restrict__ Xl,
    const bf16_t* __restrict__ QWh, const bf16_t* __restrict__ QWl,
    const bf16_t* __restrict__ KWh, const bf16_t* __restrict__ KWl,
    const bf16_t* __restrict__ VWh,
    const int* __restrict__ tokpos, const float* __restrict__ ropeT,
    bf16_t* __restrict__ Oq_h, bf16_t* __restrict__ Oq_l,
    bf16_t* __restrict__ Ok_h, bf16_t* __restrict__ Ok_l,
    bf16_t* __restrict__ Vt)
{
  __shared__ __align__(16) bf16_t sA[128 * 64];
  __shared__ __align__(16) bf16_t sB[128 * 64];

  const int tid = threadIdx.x;
  const int lane = tid & 63, wv = tid >> 6;
  const int wr = wv >> 1, wc = wv & 1;
  const int la = lane & 15, lb = lane >> 4;
  const int row0 = blockIdx.x * 128, col0 = blockIdx.y * 128;
  const int z = blockIdx.z;

  const int srow = wv * 32 + (lane >> 3);   // + i*8
  const int schk = lane & 7;                // physical 16B chunk within row

  f32x4 acc[4][4] = {};

  const int NT = (z == 2) ? 16 : 48;        // steps of BK=64 (3 segs for Q/K)

  for (int t = 0; t < NT; ++t) {
    const int seg = t >> 4;
    const int k0 = (t & 15) << 6;
    const bf16_t* Ap = (z < 2 && seg == 2) ? Xl : Xh;
    const bf16_t* Wp = (z == 2) ? VWh
                     : (z == 1) ? ((seg == 1) ? KWl : KWh)
                                : ((seg == 1) ? QWl : QWh);
    __syncthreads();
    #pragma unroll
    for (int i = 0; i < 4; ++i) {
      const int r = srow + i * 8;
      const int cs_ = (schk ^ (r & 7)) * 8;       // inverse-swizzled source col
      __builtin_amdgcn_global_load_lds(
          (gaddr_t)(Ap + (size_t)(row0 + r) * 1024 + k0 + cs_),
          (saddr_t)(sA + wv * 2048 + i * 512), 16, 0, 0);
      __builtin_amdgcn_global_load_lds(
          (gaddr_t)(Wp + (size_t)(col0 + r) * 1024 + k0 + cs_),
          (saddr_t)(sB + wv * 2048 + i * 512), 16, 0, 0);
    }
    __syncthreads();

    #pragma unroll
    for (int ks = 0; ks < 2; ++ks) {
      bf16x8 af[4];
      #pragma unroll
      for (int m = 0; m < 4; ++m) {
        const int r = wr * 64 + m * 16 + la;
        af[m] = *(const bf16x8*)&sA[r * 64 + (((ks * 4 + lb) ^ (la & 7)) * 8)];
      }
      #pragma unroll
      for (int n = 0; n < 4; ++n) {
        const int r = wc * 64 + n * 16 + la;
        const bf16x8 bfr = *(const bf16x8*)&sB[r * 64 + (((ks * 4 + lb) ^ (la & 7)) * 8)];
        #pragma unroll
        for (int m = 0; m < 4; ++m)
          acc[m][n] = __builtin_amdgcn_mfma_f32_16x16x32_bf16(af[m], bfr, acc[m][n], 0, 0, 0);
      }
    }
  }

  // ---- epilogue ----
  #pragma unroll
  for (int n = 0; n < 4; ++n) {
    const int gn = col0 + wc * 64 + n * 16 + la;
    #pragma unroll
    for (int m = 0; m < 4; ++m) {
      const int gm0 = row0 + wr * 64 + m * 16 + lb * 4;
      if (z == 2) {
        // V^T layout: [B,H,D,S], packed 8B stores
        const int b = gm0 >> 11, s0 = gm0 & 2047;
        const int h = gn >> 6, d = gn & 63;
        bf16x4 v;
        #pragma unroll
        for (int j = 0; j < 4; ++j) v[j] = (bf16_t)acc[m][n][j];
        *(bf16x4*)&Vt[(((size_t)b * 16 + h) * 64 + d) * 2048 + s0] = v;
      } else {
        const int d = gn & 63, h = gn >> 6;
        const bool odd = d & 1;
        bf16_t* Oh = z ? Ok_h : Oq_h;
        bf16_t* Ol = z ? Ok_l : Oq_l;
        #pragma unroll
        for (int j = 0; j < 4; ++j) {
          const int gm = gm0 + j;
          const float t = acc[m][n][j];
          const float other = __shfl_xor(t, 1, 64);   // partner column d^1
          const int pos = tokpos[gm];
          const f32x2 cs2 = *(const f32x2*)&ropeT[((size_t)pos << 6) + ((d >> 1) << 1)];
          const float r = odd ? (other * cs2[1] + t * cs2[0])
                              : (t * cs2[0] - other * cs2[1]);
          const bf16_t hb = (bf16_t)r;
          const int b = gm >> 11, s = gm & 2047;
          const size_t oi = (((size_t)b * 16 + h) * 2048 + s) * 64 + d;
          Oh[oi] = hb;
          Ol[oi] = (bf16_t)(r - (float)hb);
        }
      }
    }
  }
}

// ------------- O projection GEMM (bf16 A, fp32 out), m97 single-buffer -------------
__global__ __launch_bounds__(256, 4) void gemm_o(
    const bf16_t* __restrict__ Ag, const bf16_t* __restrict__ Wg,
    float* __restrict__ Of)
{
  __shared__ __align__(16) bf16_t sA[128 * 64];
  __shared__ __align__(16) bf16_t sB[128 * 64];

  const int tid = threadIdx.x;
  const int lane = tid & 63, wv = tid >> 6;
  const int wr = wv >> 1, wc = wv & 1;
  const int la = lane & 15, lb = lane >> 4;
  const int row0 = blockIdx.x * 128, col0 = blockIdx.y * 128;

  const int srow = wv * 32 + (lane >> 3);
  const int schk = lane & 7;

  f32x4 acc[4][4] = {};

  for (int t = 0; t < 16; ++t) {
    const int k0 = t << 6;
    __syncthreads();
    #pragma unroll
    for (int i = 0; i < 4; ++i) {
      const int r = srow + i * 8;
      const int cs_ = (schk ^ (r & 7)) * 8;
      __builtin_amdgcn_global_load_lds(
          (gaddr_t)(Ag + (size_t)(row0 + r) * 1024 + k0 + cs_),
          (saddr_t)(sA + wv * 2048 + i * 512), 16, 0, 0);
      __builtin_amdgcn_global_load_lds(
          (gaddr_t)(Wg + (size_t)(col0 + r) * 1024 + k0 + cs_),
          (saddr_t)(sB + wv * 2048 + i * 512), 16, 0, 0);
    }
    __syncthreads();
    #pragma unroll
    for (int ks = 0; ks < 2; ++ks) {
      bf16x8 af[4];
      #pragma unroll
      for (int m = 0; m < 4; ++m) {
        const int r = wr * 64 + m * 16 + la;
        af[m] = *(const bf16x8*)&sA[r * 64 + (((ks * 4 + lb) ^ (la & 7)) * 8)];
      }
      #pragma unroll
      for (int n = 0; n < 4; ++n) {
        const int r = wc * 64 + n * 16 + la;
        const bf16x8 bfr = *(const bf16x8*)&sB[r * 64 + (((ks * 4 + lb) ^ (la & 7)) * 8)];
        #pragma unroll
        for (int m = 0; m < 4; ++m)
          acc[m][n] = __builtin_amdgcn_mfma_f32_16x16x32_bf16(af[m], bfr, acc[m][n], 0, 0, 0);
      }
    }
  }

  #pragma unroll
  for (int n = 0; n < 4; ++n) {
    const int gn = col0 + wc * 64 + n * 16 + la;
    #pragma unroll
    for (int m = 0; m < 4; ++m) {
      const int gm0 = row0 + wr * 64 + m * 16 + lb * 4;
      #pragma unroll
      for (int j = 0; j < 4; ++j)
        Of[(size_t)(gm0 + j) * 1024 + gn] = acc[m][n][j];
    }
  }
}

// XOR swizzle for 64-elem-wide bf16 LDS tiles (row = 128B).
__device__ __forceinline__ int SW(int e) { return e ^ (((e >> 6) & 7) << 3); }

__device__ __forceinline__ u32 pk2(float a, float b) {
  bf16x2 t; t[0] = (bf16_t)a; t[1] = (bf16_t)b;
  return __builtin_bit_cast(u32, t);
}

// Flash attention, causal, split-bf16 QK^T, swapped operands, 32x32x16 MFMA.
// Grid 1024 blocks x 256 threads (4 waves x 32 q-rows = QBLK 128), KVBLK=64.
__global__ __launch_bounds__(256) void attn_kernel(
    const bf16_t* __restrict__ Qhi, const bf16_t* __restrict__ Qlo,
    const bf16_t* __restrict__ Khi, const bf16_t* __restrict__ Klo,
    const bf16_t* __restrict__ Vt, bf16_t* __restrict__ O)
{
  __shared__ __align__(16) bf16_t sKV[2][3 * 4096];  // Kh | Kl | Vt

  // XCD-aware remap + longest-first qb
  const int linear = (int)blockIdx.y * (int)gridDim.x + (int)blockIdx.x;
  const int xcd = linear & 7;
  const int pos = linear >> 3;            // 0..127
  const int bh  = xcd * 8 + (pos >> 4);   // [0,64)
  const int qb  = 15 - (pos & 15);
  const int b = bh >> 4, h = bh & 15;

  const size_t base = (size_t)bh * 2048 * 64;
  const bf16_t* Qh_ = Qhi + base;
  const bf16_t* Ql_ = Qlo + base;
  const bf16_t* Kh_ = Khi + base;
  const bf16_t* Kl_ = Klo + base;
  const bf16_t* Vt_ = Vt + base;          // [64 d][2048 s]

  const int tid = threadIdx.x, wv = tid >> 6, lane = tid & 63;
  const int q32 = lane & 31, l5 = lane >> 5;
  const int q = qb * 128 + wv * 32 + q32;

  // staging geometry: 6 x 16B per thread covers 24KB (Kh,Kl,Vt x 8KB)
  auto STAGE = [&](int kvb, int buf) {
    const int kv0 = kvb * 64;
    bf16_t* dst = &sKV[buf][0];
    #pragma unroll
    for (int i = 0; i < 2; ++i) {
      const int e0 = (i * 4 + wv) * 512;          // wave-uniform chunk base
      const int e = e0 + lane * 8;
      const int r = e >> 6;                       // tile row 0..63
      const int csw = ((e >> 3) & 7) ^ (r & 7);   // inverse-swizzled chunk
      const int ks = r * 64 + csw * 8;
      __builtin_amdgcn_global_load_lds((gaddr_t)(Kh_ + (size_t)kv0 * 64 + ks),
                                       (saddr_t)(dst + e0), 16, 0, 0);
      __builtin_amdgcn_global_load_lds((gaddr_t)(Kl_ + (size_t)kv0 * 64 + ks),
                                       (saddr_t)(dst + 4096 + e0), 16, 0, 0);
      __builtin_amdgcn_global_load_lds((gaddr_t)(Vt_ + (size_t)r * 2048 + kv0 + csw * 8),
                                       (saddr_t)(dst + 8192 + e0), 16, 0, 0);
    }
  };

  const int nt = 2 * qb + 2;
  STAGE(0, 0);

  // Q fragments: B-operand, lane holds Q[k = kc*16 + l5*8 + 0..7][q]
  bf16x8 qh[4], ql[4];
  #pragma unroll
  for (int kc = 0; kc < 4; ++kc) {
    qh[kc] = *(const bf16x8*)&Qh_[(size_t)q * 64 + kc * 16 + l5 * 8];
    ql[kc] = *(const bf16x8*)&Ql_[(size_t)q * 64 + kc * 16 + l5 * 8];
  }

  f32x16 oacc[2] = {};        // O^T[d = 32*dh + (r&3)+8*(r>>2)+4*l5][q]
  float m2 = -1e30f, l = 0.f; // exp2-domain running max / denom
  const float CSC = 0.125f * 1.44269504089f;

  for (int kvb = 0; kvb < nt; ++kvb) {
    const int kv0 = kvb * 64;
    __syncthreads();                       // stage(kvb) ready; buf^1 free
    if (kvb + 1 < nt) STAGE(kvb + 1, (kvb + 1) & 1);

    const bf16_t* sKh = &sKV[kvb & 1][0];
    const bf16_t* sKl = sKh + 4096;
    const bf16_t* sVt = sKh + 8192;

    // S^T = K Q^T (3-term split)
    f32x16 sacc[2] = {};
    __builtin_amdgcn_s_setprio(1);
    #pragma unroll
    for (int hv = 0; hv < 2; ++hv) {
      #pragma unroll
      for (int kc = 0; kc < 4; ++kc) {
        const int rr = SW((hv * 32 + q32) * 64 + kc * 16 + l5 * 8);
        const bf16x8 kh = *(const bf16x8*)&sKh[rr];
        const bf16x8 kl = *(const bf16x8*)&sKl[rr];
        sacc[hv] = __builtin_amdgcn_mfma_f32_32x32x16_bf16(kh, qh[kc], sacc[hv], 0, 0, 0);
        sacc[hv] = __builtin_amdgcn_mfma_f32_32x32x16_bf16(kl, qh[kc], sacc[hv], 0, 0, 0);
        sacc[hv] = __builtin_amdgcn_mfma_f32_32x32x16_bf16(kh, ql[kc], sacc[hv], 0, 0, 0);
      }
    }
    __builtin_amdgcn_s_setprio(0);

    // scale into exp2 domain + causal mask (only possibly-diagonal tiles)
    if (kvb >= 2 * qb) {
      #pragma unroll
      for (int hv = 0; hv < 2; ++hv)
        #pragma unroll
        for (int r = 0; r < 16; ++r) {
          const int kv = kv0 + 32 * hv + (r & 3) + 8 * (r >> 2) + 4 * l5;
          sacc[hv][r] = (kv <= q) ? sacc[hv][r] * CSC : -1e30f;
        }
    } else {
      #pragma unroll
      for (int hv = 0; hv < 2; ++hv)
        #pragma unroll
        for (int r = 0; r < 16; ++r) sacc[hv][r] *= CSC;
    }

    // row max: 32 in-lane + one cross-half shfl
    float red = sacc[0][0];
    #pragma unroll
    for (int hv = 0; hv < 2; ++hv)
      #pragma unroll
      for (int r = 0; r < 16; ++r) red = fmaxf(red, sacc[hv][r]);
    red = fmaxf(red, __shfl_xor(red, 32, 64));

    // defer-max (THR = 8*log2e ~ 11.5 in exp2 domain)
    const float mn = fmaxf(m2, red);
    if (!__all(mn - m2 <= 11.5f)) {
      const float sf = exp2f(m2 - mn);
      m2 = mn;
      l *= sf;
      #pragma unroll
      for (int dh = 0; dh < 2; ++dh)
        #pragma unroll
        for (int r = 0; r < 16; ++r) oacc[dh][r] *= sf;
    }

    float rs = 0.f;
    #pragma unroll
    for (int hv = 0; hv < 2; ++hv)
      #pragma unroll
      for (int r = 0; r < 16; ++r) {
        const float p = exp2f(sacc[hv][r] - m2);
        sacc[hv][r] = p;
        rs += p;
      }
    rs += __shfl_xor(rs, 32, 64);
    l += rs;

    // pack P to bf16 pairs: pk[hv][g][j] covers kv = 32hv+8g+4*l5+{2j,2j+1}
    u32 pk[2][4][2];
    #pragma unroll
    for (int hv = 0; hv < 2; ++hv)
      #pragma unroll
      for (int g = 0; g < 4; ++g) {
        pk[hv][g][0] = pk2(sacc[hv][4 * g], sacc[hv][4 * g + 1]);
        pk[hv][g][1] = pk2(sacc[hv][4 * g + 2], sacc[hv][4 * g + 3]);
      }

    // O^T += V^T P^T, B-frag per k-chunk c assembled in-register
    __builtin_amdgcn_s_setprio(1);
    #pragma unroll
    for (int c = 0; c < 4; ++c) {
      const int i0 = 2 * c, i1 = 2 * c + 1;
      const int h0 = i0 >> 2, g0 = i0 & 3, h1 = i1 >> 2, g1 = i1 & 3;
      const u32 own_a = l5 ? pk[h1][g1][0] : pk[h0][g0][0];
      const u32 own_b = l5 ? pk[h1][g1][1] : pk[h0][g0][1];
      const u32 snd_a = l5 ? pk[h0][g0][0] : pk[h1][g1][0];
      const u32 snd_b = l5 ? pk[h0][g0][1] : pk[h1][g1][1];
      const u32 rcv_a = (u32)__shfl_xor((int)snd_a, 32, 64);
      const u32 rcv_b = (u32)__shfl_xor((int)snd_b, 32, 64);
      u32x4 w4;
      w4[0] = l5 ? rcv_a : own_a;   // kv offset +0..1 (mod-8 half 0)
      w4[1] = l5 ? rcv_b : own_b;   // +2..3
      w4[2] = l5 ? own_a : rcv_a;   // +4..5 (mod-8 half 1)
      w4[3] = l5 ? own_b : rcv_b;   // +6..7
      const bf16x8 pfrag = __builtin_bit_cast(bf16x8, w4);
      #pragma unroll
      for (int dh = 0; dh < 2; ++dh) {
        const int rr = SW((dh * 32 + q32) * 64 + c * 16 + l5 * 8);
        const bf16x8 va = *(const bf16x8*)&sVt[rr];
        oacc[dh] = __builtin_amdgcn_mfma_f32_32x32x16_bf16(va, pfrag, oacc[dh], 0, 0, 0);
      }
    }
    __builtin_amdgcn_s_setprio(0);
  }

  // epilogue: O[b,s,h,d] bf16, packed b64 (d groups of 4)
  const float inv_l = 1.0f / l;
  #pragma unroll
  for (int dh = 0; dh < 2; ++dh)
    #pragma unroll
    for (int g = 0; g < 4; ++g) {
      bf16x4 ov;
      #pragma unroll
      for (int j = 0; j < 4; ++j) ov[j] = (bf16_t)(oacc[dh][4 * g + j] * inv_l);
      const int d0 = 32 * dh + 8 * g + 4 * l5;
      *(bf16x4*)&O[(((size_t)b * 2048 + q) * 16 + h) * 64 + d0] = ov;
    }
}

extern "C" void kernel_launch(void* const* d_in, const int* in_sizes, int n_in,
                              void* d_out, int out_size, void* d_ws, size_t ws_size,
                              hipStream_t stream)
{
  const float* x      = (const float*)d_in[0];
  const int*   tokpos = (const int*)d_in[1];
  const float* qw     = (const float*)d_in[2];
  const float* kw     = (const float*)d_in[3];
  const float* vw     = (const float*)d_in[4];
  const float* ow     = (const float*)d_in[5];
  float* out = (float*)d_out;

  const size_t E  = (size_t)4 * 16 * 2048 * 64;  // 8388608 elems per activation
  const size_t W1 = (size_t)1024 * 1024;         // weight elems
  bf16_t* base = (bf16_t*)d_ws;
  bf16_t* Qhi = base;
  bf16_t* Qlo = base + E;
  bf16_t* Khi = base + 2 * E;
  bf16_t* Klo = base + 3 * E;
  bf16_t* Vt  = base + 4 * E;        // [B,H,D,S]
  bf16_t* Xh  = base + 5 * E;
  bf16_t* Xl  = base + 6 * E;
  bf16_t* QWh = base + 7 * E;
  bf16_t* QWl = QWh + W1;
  bf16_t* KWh = QWh + 2 * W1;
  bf16_t* KWl = QWh + 3 * W1;
  bf16_t* VWh = QWh + 4 * W1;
  bf16_t* OWh = QWh + 5 * W1;
  float*  ropeT = (float*)(QWh + 6 * W1);        // 2048*64 floats
  bf16_t* O = Xh;                                 // alias: X dead before attn

  RopeTab tab;
  for (int i = 0; i < 32; ++i)
    tab.inv[i] = (float)pow(10000.0, -(double)i / 32.0);

  // fused pre-passes (splits + rope table)
  prep_k<<<12544, 256, 0, stream>>>(x, qw, kw, vw, ow, tab,
                                    Xh, Xl, QWh, QWl, KWh, KWl, VWh, OWh, ropeT);

  // Q, K, V projections in one launch (z selects); RoPE fused for Q/K
  gemm_qkv<<<dim3(64, 8, 3), 256, 0, stream>>>(
      Xh, Xl, QWh, QWl, KWh, KWl, VWh, tokpos, ropeT,
      Qhi, Qlo, Khi, Klo, Vt);
  // attention (1024 blocks x 256 threads, XCD-remapped inside)
  attn_kernel<<<dim3(16, 64), 256, 0, stream>>>(Qhi, Qlo, Khi, Klo, Vt, O);
  // output projection -> fp32 d_out
  gemm_o<<<dim3(64, 8), 256, 0, stream>>>(O, OWh, out);
}

// Round 8
// 241.674 us; speedup vs baseline: 2.0494x; 1.4032x over previous
//
#include <hip/hip_runtime.h>
#include <cmath>

// MHA fused forward, MI355X gfx950.
// R7: attn reverted to the R4 16x16/8-wave structure (the R5/R6 32x32
//     rewrite collapsed occupancy 25->8.5% and doubled the per-wave VALU
//     chain; 204us vs 143us). New: paired-qb persistent blocks -- 512
//     blocks (exactly 2/CU), each does qb=15-p then qb=p for one bh =
//     uniform 34 kv-tiles/block, killing the causal-imbalance tail.
// GEMMs / pre-pass unchanged from R6 (m97 single-buffer 32KB, z=3 merge).
// Numerics: split-bf16 hi/lo 3-term for Q/K projections and QK^T.

typedef __bf16 bf16_t;
typedef __bf16 bf16x2 __attribute__((ext_vector_type(2)));
typedef __bf16 bf16x4 __attribute__((ext_vector_type(4)));
typedef __bf16 bf16x8 __attribute__((ext_vector_type(8)));
typedef float f32x2 __attribute__((ext_vector_type(2)));
typedef float f32x4 __attribute__((ext_vector_type(4)));
typedef unsigned int u32;
typedef const __attribute__((address_space(1))) u32* gaddr_t;
typedef __attribute__((address_space(3))) u32* saddr_t;

struct RopeTab { float inv[32]; };

// ---------------- fused pre-pass ----------------
__device__ __forceinline__ void split4(const float* __restrict__ in,
                                       bf16_t* __restrict__ hi,
                                       bf16_t* __restrict__ lo, bool LO,
                                       int blk, int tid)
{
  const int i = blk * 256 + tid;
  const f32x4 u = *(const f32x4*)(in + (size_t)i * 4);
  bf16x4 h, l;
  #pragma unroll
  for (int j = 0; j < 4; ++j) {
    const bf16_t hb = (bf16_t)u[j];
    h[j] = hb;
    if (LO) l[j] = (bf16_t)(u[j] - (float)hb);
  }
  *(bf16x4*)(hi + (size_t)i * 4) = h;
  if (LO) *(bf16x4*)(lo + (size_t)i * 4) = l;
}

__global__ __launch_bounds__(256) void prep_k(
    const float* __restrict__ x,  const float* __restrict__ qw,
    const float* __restrict__ kw, const float* __restrict__ vw,
    const float* __restrict__ ow, RopeTab tab,
    bf16_t* __restrict__ Xh,  bf16_t* __restrict__ Xl,
    bf16_t* __restrict__ QWh, bf16_t* __restrict__ QWl,
    bf16_t* __restrict__ KWh, bf16_t* __restrict__ KWl,
    bf16_t* __restrict__ VWh, bf16_t* __restrict__ OWh,
    float* __restrict__ ropeT)
{
  const int bid = blockIdx.x, tid = threadIdx.x;
  if (bid < 8192)       split4(x,  Xh,  Xl,  true,  bid,         tid);
  else if (bid < 9216)  split4(qw, QWh, QWl, true,  bid - 8192,  tid);
  else if (bid < 10240) split4(kw, KWh, KWl, true,  bid - 9216,  tid);
  else if (bid < 11264) split4(vw, VWh, nullptr, false, bid - 10240, tid);
  else if (bid < 12288) split4(ow, OWh, nullptr, false, bid - 11264, tid);
  else {
    const int i = (bid - 12288) * 256 + tid;   // 2048*32 entries
    const int p = i >> 5, d2 = i & 31;
    float sn, cs;
    sincosf((float)p * tab.inv[d2], &sn, &cs);
    ropeT[(size_t)i * 2]     = cs;
    ropeT[(size_t)i * 2 + 1] = sn;
  }
}

// ------------- QKV projection GEMM (B^T), m97 single-buffer -------------
// z=0: Q (3-seg split, RoPE epilogue), z=1: K (same), z=2: V (1 seg, V^T out).
__global__ __launch_bounds__(256, 4) void gemm_qkv(
    const bf16_t* __restrict__ Xh, const bf16_t* __restrict__ Xl,
    const bf16_t* __restrict__ QWh, const bf16_t* __restrict__ QWl,
    const bf16_t* __restrict__ KWh, const bf16_t* __restrict__ KWl,
    const bf16_t* __restrict__ VWh,
    const int* __restrict__ tokpos, const float* __restrict__ ropeT,
    bf16_t* __restrict__ Oq_h, bf16_t* __restrict__ Oq_l,
    bf16_t* __restrict__ Ok_h, bf16_t* __restrict__ Ok_l,
    bf16_t* __restrict__ Vt)
{
  __shared__ __align__(16) bf16_t sA[128 * 64];
  __shared__ __align__(16) bf16_t sB[128 * 64];

  const int tid = threadIdx.x;
  const int lane = tid & 63, wv = tid >> 6;
  const int wr = wv >> 1, wc = wv & 1;
  const int la = lane & 15, lb = lane >> 4;
  const int row0 = blockIdx.x * 128, col0 = blockIdx.y * 128;
  const int z = blockIdx.z;

  const int srow = wv * 32 + (lane >> 3);   // + i*8
  const int schk = lane & 7;                // physical 16B chunk within row

  f32x4 acc[4][4] = {};

  const int NT = (z == 2) ? 16 : 48;        // steps of BK=64 (3 segs for Q/K)

  for (int t = 0; t < NT; ++t) {
    const int seg = t >> 4;
    const int k0 = (t & 15) << 6;
    const bf16_t* Ap = (z < 2 && seg == 2) ? Xl : Xh;
    const bf16_t* Wp = (z == 2) ? VWh
                     : (z == 1) ? ((seg == 1) ? KWl : KWh)
                                : ((seg == 1) ? QWl : QWh);
    __syncthreads();
    #pragma unroll
    for (int i = 0; i < 4; ++i) {
      const int r = srow + i * 8;
      const int cs_ = (schk ^ (r & 7)) * 8;       // inverse-swizzled source col
      __builtin_amdgcn_global_load_lds(
          (gaddr_t)(Ap + (size_t)(row0 + r) * 1024 + k0 + cs_),
          (saddr_t)(sA + wv * 2048 + i * 512), 16, 0, 0);
      __builtin_amdgcn_global_load_lds(
          (gaddr_t)(Wp + (size_t)(col0 + r) * 1024 + k0 + cs_),
          (saddr_t)(sB + wv * 2048 + i * 512), 16, 0, 0);
    }
    __syncthreads();

    #pragma unroll
    for (int ks = 0; ks < 2; ++ks) {
      bf16x8 af[4];
      #pragma unroll
      for (int m = 0; m < 4; ++m) {
        const int r = wr * 64 + m * 16 + la;
        af[m] = *(const bf16x8*)&sA[r * 64 + (((ks * 4 + lb) ^ (la & 7)) * 8)];
      }
      #pragma unroll
      for (int n = 0; n < 4; ++n) {
        const int r = wc * 64 + n * 16 + la;
        const bf16x8 bfr = *(const bf16x8*)&sB[r * 64 + (((ks * 4 + lb) ^ (la & 7)) * 8)];
        #pragma unroll
        for (int m = 0; m < 4; ++m)
          acc[m][n] = __builtin_amdgcn_mfma_f32_16x16x32_bf16(af[m], bfr, acc[m][n], 0, 0, 0);
      }
    }
  }

  // ---- epilogue ----
  #pragma unroll
  for (int n = 0; n < 4; ++n) {
    const int gn = col0 + wc * 64 + n * 16 + la;
    #pragma unroll
    for (int m = 0; m < 4; ++m) {
      const int gm0 = row0 + wr * 64 + m * 16 + lb * 4;
      if (z == 2) {
        // V^T layout: [B,H,D,S], packed 8B stores
        const int b = gm0 >> 11, s0 = gm0 & 2047;
        const int h = gn >> 6, d = gn & 63;
        bf16x4 v;
        #pragma unroll
        for (int j = 0; j < 4; ++j) v[j] = (bf16_t)acc[m][n][j];
        *(bf16x4*)&Vt[(((size_t)b * 16 + h) * 64 + d) * 2048 + s0] = v;
      } else {
        const int d = gn & 63, h = gn >> 6;
        const bool odd = d & 1;
        bf16_t* Oh = z ? Ok_h : Oq_h;
        bf16_t* Ol = z ? Ok_l : Oq_l;
        #pragma unroll
        for (int j = 0; j < 4; ++j) {
          const int gm = gm0 + j;
          const float t = acc[m][n][j];
          const float other = __shfl_xor(t, 1, 64);   // partner column d^1
          const int pos = tokpos[gm];
          const f32x2 cs2 = *(const f32x2*)&ropeT[((size_t)pos << 6) + ((d >> 1) << 1)];
          const float r = odd ? (other * cs2[1] + t * cs2[0])
                              : (t * cs2[0] - other * cs2[1]);
          const bf16_t hb = (bf16_t)r;
          const int b = gm >> 11, s = gm & 2047;
          const size_t oi = (((size_t)b * 16 + h) * 2048 + s) * 64 + d;
          Oh[oi] = hb;
          Ol[oi] = (bf16_t)(r - (float)hb);
        }
      }
    }
  }
}

// ------------- O projection GEMM (bf16 A, fp32 out), m97 single-buffer -------------
__global__ __launch_bounds__(256, 4) void gemm_o(
    const bf16_t* __restrict__ Ag, const bf16_t* __restrict__ Wg,
    float* __restrict__ Of)
{
  __shared__ __align__(16) bf16_t sA[128 * 64];
  __shared__ __align__(16) bf16_t sB[128 * 64];

  const int tid = threadIdx.x;
  const int lane = tid & 63, wv = tid >> 6;
  const int wr = wv >> 1, wc = wv & 1;
  const int la = lane & 15, lb = lane >> 4;
  const int row0 = blockIdx.x * 128, col0 = blockIdx.y * 128;

  const int srow = wv * 32 + (lane >> 3);
  const int schk = lane & 7;

  f32x4 acc[4][4] = {};

  for (int t = 0; t < 16; ++t) {
    const int k0 = t << 6;
    __syncthreads();
    #pragma unroll
    for (int i = 0; i < 4; ++i) {
      const int r = srow + i * 8;
      const int cs_ = (schk ^ (r & 7)) * 8;
      __builtin_amdgcn_global_load_lds(
          (gaddr_t)(Ag + (size_t)(row0 + r) * 1024 + k0 + cs_),
          (saddr_t)(sA + wv * 2048 + i * 512), 16, 0, 0);
      __builtin_amdgcn_global_load_lds(
          (gaddr_t)(Wg + (size_t)(col0 + r) * 1024 + k0 + cs_),
          (saddr_t)(sB + wv * 2048 + i * 512), 16, 0, 0);
    }
    __syncthreads();
    #pragma unroll
    for (int ks = 0; ks < 2; ++ks) {
      bf16x8 af[4];
      #pragma unroll
      for (int m = 0; m < 4; ++m) {
        const int r = wr * 64 + m * 16 + la;
        af[m] = *(const bf16x8*)&sA[r * 64 + (((ks * 4 + lb) ^ (la & 7)) * 8)];
      }
      #pragma unroll
      for (int n = 0; n < 4; ++n) {
        const int r = wc * 64 + n * 16 + la;
        const bf16x8 bfr = *(const bf16x8*)&sB[r * 64 + (((ks * 4 + lb) ^ (la & 7)) * 8)];
        #pragma unroll
        for (int m = 0; m < 4; ++m)
          acc[m][n] = __builtin_amdgcn_mfma_f32_16x16x32_bf16(af[m], bfr, acc[m][n], 0, 0, 0);
      }
    }
  }

  #pragma unroll
  for (int n = 0; n < 4; ++n) {
    const int gn = col0 + wc * 64 + n * 16 + la;
    #pragma unroll
    for (int m = 0; m < 4; ++m) {
      const int gm0 = row0 + wr * 64 + m * 16 + lb * 4;
      #pragma unroll
      for (int j = 0; j < 4; ++j)
        Of[(size_t)(gm0 + j) * 1024 + gn] = acc[m][n][j];
    }
  }
}

// XOR swizzle for 64-elem-wide bf16 LDS tiles (row = 128B).
__device__ __forceinline__ int SW(int e) { return e ^ (((e >> 6) & 7) << 3); }

// Flash attention, causal, split-bf16 QK^T, swapped operands (R4 structure).
// 512 persistent blocks x 512 threads. QBLK=128 (8 waves x 16 q-rows),
// KVBLK=64, double-buffered K/V prefetch. Each block processes TWO q-blocks
// of one bh: qb=15-p then qb=p -> uniform 34 tiles per block (no tail).
__global__ __launch_bounds__(512, 4) void attn_kernel(
    const bf16_t* __restrict__ Qhi, const bf16_t* __restrict__ Qlo,
    const bf16_t* __restrict__ Khi, const bf16_t* __restrict__ Klo,
    const bf16_t* __restrict__ Vt, bf16_t* __restrict__ O)
{
  // [buf][ Kh(4096) | Kl(4096) | Vt(4096) ]
  __shared__ __align__(16) bf16_t sKV[2][3 * 4096];
  __shared__ __align__(16) bf16_t sP[8 * 1024];   // per-wave [q=la][kv], la-swizzled

  // XCD-aware remap: 512 blocks = 64 bh x 8 qb-pairs
  const int linear = (int)blockIdx.x;
  const int xcd = linear & 7;
  const int pos = linear >> 3;            // 0..63
  const int bh  = xcd * 8 + (pos >> 3);   // [0,64)
  const int p   = pos & 7;                // qb pair index
  const int b = bh >> 4, h = bh & 15;

  const size_t base = (size_t)bh * 2048 * 64;
  const bf16_t* Qh_ = Qhi + base;
  const bf16_t* Ql_ = Qlo + base;
  const bf16_t* Kh_ = Khi + base;
  const bf16_t* Kl_ = Klo + base;
  const bf16_t* Vt_ = Vt + base;    // [64 d][2048 s]

  const int tid = threadIdx.x, wv = tid >> 6, lane = tid & 63;
  const int la = lane & 15, lb = lane >> 4;

  // staging geometry (per thread, 3 x 16B): covers 24KB over 512 threads
  const int sr   = wv * 8 + (lane >> 3);        // tile row 0..63
  const int scsw = (lane & 7) ^ (sr & 7);       // inverse-swizzled 16B chunk
  const int ssrc = sr * 64 + scsw * 8;          // K source elem offset in tile
  const int se0  = wv * 512;                    // wave-uniform LDS chunk base
  const int psw  = (la & 7) << 3;               // sP swizzle key (kv bits 3..5)

  auto STAGE = [&](int kvb, int buf) {
    const int kv0 = kvb * 64;
    bf16_t* dst = &sKV[buf][0];
    __builtin_amdgcn_global_load_lds((gaddr_t)(Kh_ + (size_t)kv0 * 64 + ssrc),
                                     (saddr_t)(dst + se0), 16, 0, 0);
    __builtin_amdgcn_global_load_lds((gaddr_t)(Kl_ + (size_t)kv0 * 64 + ssrc),
                                     (saddr_t)(dst + 4096 + se0), 16, 0, 0);
    __builtin_amdgcn_global_load_lds((gaddr_t)(Vt_ + (size_t)sr * 2048 + kv0 + scsw * 8),
                                     (saddr_t)(dst + 8192 + se0), 16, 0, 0);
  };

  for (int half = 0; half < 2; ++half) {
    const int qb = half ? p : 15 - p;
    const int q = qb * 128 + wv * 16 + la;   // this lane's q row (global)
    bf16x8 qh[2], ql[2];
    #pragma unroll
    for (int kf = 0; kf < 2; ++kf) {
      qh[kf] = *(const bf16x8*)&Qh_[(size_t)q * 64 + kf * 32 + lb * 8];
      ql[kf] = *(const bf16x8*)&Ql_[(size_t)q * 64 + kf * 32 + lb * 8];
    }

    f32x4 oacc[4] = {};       // oacc[nf][j] = O^T[d = nf*16+lb*4+j][q = la]
    float m = -1e30f, l = 0.f;
    const int nt = 2 * qb + 2;

    STAGE(0, 0);
    __syncthreads();

    for (int kvb = 0; kvb < nt; ++kvb) {
      const int kv0 = kvb * 64;
      if (kvb + 1 < nt) STAGE(kvb + 1, (kvb + 1) & 1);

      const bf16_t* sKh = &sKV[kvb & 1][0];
      const bf16_t* sKl = sKh + 4096;
      const bf16_t* sVt = sKh + 8192;

      // S^T = K Q^T (3-term split): sacc[nf][j] at kv = kv0+nf*16+lb*4+j
      f32x4 sacc[4] = {};
      __builtin_amdgcn_s_setprio(1);
      #pragma unroll
      for (int nf = 0; nf < 4; ++nf) {
        #pragma unroll
        for (int kf = 0; kf < 2; ++kf) {
          const int rr = SW((nf * 16 + la) * 64 + kf * 32 + lb * 8);
          const bf16x8 kh = *(const bf16x8*)&sKh[rr];
          const bf16x8 kl = *(const bf16x8*)&sKl[rr];
          sacc[nf] = __builtin_amdgcn_mfma_f32_16x16x32_bf16(kh, qh[kf], sacc[nf], 0, 0, 0);
          sacc[nf] = __builtin_amdgcn_mfma_f32_16x16x32_bf16(kl, qh[kf], sacc[nf], 0, 0, 0);
          sacc[nf] = __builtin_amdgcn_mfma_f32_16x16x32_bf16(kh, ql[kf], sacc[nf], 0, 0, 0);
        }
      }
      __builtin_amdgcn_s_setprio(0);

      // mask + scale (mask only possibly-diagonal tiles: kvb >= 2*qb)
      if (kvb >= 2 * qb) {
        #pragma unroll
        for (int nf = 0; nf < 4; ++nf)
          #pragma unroll
          for (int j = 0; j < 4; ++j) {
            const int kvi = kv0 + nf * 16 + lb * 4 + j;
            sacc[nf][j] = (kvi <= q) ? sacc[nf][j] * 0.125f : -1e30f;
          }
      } else {
        #pragma unroll
        for (int nf = 0; nf < 4; ++nf)
          #pragma unroll
          for (int j = 0; j < 4; ++j) sacc[nf][j] *= 0.125f;
      }

      // row softmax: in-lane 16, then combine lb groups (lanes ^16, ^32)
      float red = sacc[0][0];
      #pragma unroll
      for (int nf = 0; nf < 4; ++nf)
        #pragma unroll
        for (int j = 0; j < 4; ++j) red = fmaxf(red, sacc[nf][j]);
      red = fmaxf(red, __shfl_xor(red, 16, 64));
      red = fmaxf(red, __shfl_xor(red, 32, 64));

      // defer-max (T13): only rescale when the max grew by more than THR=8
      const float mn = fmaxf(m, red);
      if (!__all(mn - m <= 8.0f)) {
        const float sf = __expf(m - mn);
        m = mn;
        l *= sf;
        #pragma unroll
        for (int nf = 0; nf < 4; ++nf)
          #pragma unroll
          for (int j = 0; j < 4; ++j) oacc[nf][j] *= sf;
      }

      float rs = 0.f;
      #pragma unroll
      for (int nf = 0; nf < 4; ++nf)
        #pragma unroll
        for (int j = 0; j < 4; ++j) {
          const float pj = __expf(sacc[nf][j] - m);
          sacc[nf][j] = pj;
          rs += pj;
        }
      rs += __shfl_xor(rs, 16, 64);
      rs += __shfl_xor(rs, 32, 64);
      l += rs;

      // P -> LDS: packed b64 per nf (4 consecutive kv), la-keyed swizzle
      #pragma unroll
      for (int nf = 0; nf < 4; ++nf) {
        bf16x4 pv;
        #pragma unroll
        for (int j = 0; j < 4; ++j) pv[j] = (bf16_t)sacc[nf][j];
        *(bf16x4*)&sP[wv * 1024 + la * 64 + ((nf * 16 + lb * 4) ^ psw)] = pv;
      }

      // O^T += V^T P^T : mfma(A=Vt rows d, B=P rows q)
      __builtin_amdgcn_s_setprio(1);
      #pragma unroll
      for (int ks = 0; ks < 2; ++ks) {
        const bf16x8 pa = *(const bf16x8*)&sP[wv * 1024 + la * 64 + ((ks * 32 + lb * 8) ^ psw)];
        #pragma unroll
        for (int nf = 0; nf < 4; ++nf) {
          const bf16x8 vb2 = *(const bf16x8*)&sVt[SW((nf * 16 + la) * 64 + ks * 32 + lb * 8)];
          oacc[nf] = __builtin_amdgcn_mfma_f32_16x16x32_bf16(vb2, pa, oacc[nf], 0, 0, 0);
        }
      }
      __builtin_amdgcn_s_setprio(0);

      __syncthreads();   // drains prefetch (vmcnt) + guards buffer overwrite
    }

    // epilogue: O[b,s,h,d] bf16, packed b64 (4 consecutive d per nf)
    const float inv_l = 1.0f / l;
    #pragma unroll
    for (int nf = 0; nf < 4; ++nf) {
      bf16x4 ov;
      #pragma unroll
      for (int j = 0; j < 4; ++j) ov[j] = (bf16_t)(oacc[nf][j] * inv_l);
      const int d0 = nf * 16 + lb * 4;
      *(bf16x4*)&O[(((size_t)b * 2048 + q) * 16 + h) * 64 + d0] = ov;
    }
  }
}

extern "C" void kernel_launch(void* const* d_in, const int* in_sizes, int n_in,
                              void* d_out, int out_size, void* d_ws, size_t ws_size,
                              hipStream_t stream)
{
  const float* x      = (const float*)d_in[0];
  const int*   tokpos = (const int*)d_in[1];
  const float* qw     = (const float*)d_in[2];
  const float* kw     = (const float*)d_in[3];
  const float* vw     = (const float*)d_in[4];
  const float* ow     = (const float*)d_in[5];
  float* out = (float*)d_out;

  const size_t E  = (size_t)4 * 16 * 2048 * 64;  // 8388608 elems per activation
  const size_t W1 = (size_t)1024 * 1024;         // weight elems
  bf16_t* base = (bf16_t*)d_ws;
  bf16_t* Qhi = base;
  bf16_t* Qlo = base + E;
  bf16_t* Khi = base + 2 * E;
  bf16_t* Klo = base + 3 * E;
  bf16_t* Vt  = base + 4 * E;        // [B,H,D,S]
  bf16_t* Xh  = base + 5 * E;
  bf16_t* Xl  = base + 6 * E;
  bf16_t* QWh = base + 7 * E;
  bf16_t* QWl = QWh + W1;
  bf16_t* KWh = QWh + 2 * W1;
  bf16_t* KWl = QWh + 3 * W1;
  bf16_t* VWh = QWh + 4 * W1;
  bf16_t* OWh = QWh + 5 * W1;
  float*  ropeT = (float*)(QWh + 6 * W1);        // 2048*64 floats
  bf16_t* O = Xh;                                 // alias: X dead before attn

  RopeTab tab;
  for (int i = 0; i < 32; ++i)
    tab.inv[i] = (float)pow(10000.0, -(double)i / 32.0);

  // fused pre-passes (splits + rope table)
  prep_k<<<12544, 256, 0, stream>>>(x, qw, kw, vw, ow, tab,
                                    Xh, Xl, QWh, QWl, KWh, KWl, VWh, OWh, ropeT);

  // Q, K, V projections in one launch (z selects); RoPE fused for Q/K
  gemm_qkv<<<dim3(64, 8, 3), 256, 0, stream>>>(
      Xh, Xl, QWh, QWl, KWh, KWl, VWh, tokpos, ropeT,
      Qhi, Qlo, Khi, Klo, Vt);
  // attention: 512 persistent blocks x 512 threads (2 blocks/CU exactly)
  attn_kernel<<<512, 512, 0, stream>>>(Qhi, Qlo, Khi, Klo, Vt, O);
  // output projection -> fp32 d_out
  gemm_o<<<dim3(64, 8), 256, 0, stream>>>(O, OWh, out);
}